// Round 13
// baseline (33.254 us; speedup 1.0000x reference)
//
#include <hip/hip_runtime.h>
#include <math.h>

#define N_  2
#define A_  360
#define M_  512
#define NP_ 32
#define PS_ 64
#define PASS_A 180      // angles staged per pass (2 passes)
#define W_  24          // float2 pairs per window (16x16 span <= 21.3 + interp + slack)

// 512-thread blocks over a 16x16 region, 1024 blocks, 4 blocks/CU.
// Windows staged as {g0, g1-g0} pairs -> ONE aligned ds_read_b64 per
// pixel-angle (R7 paid two DS accesses via ds_read2_b32). Two staging
// passes of 180 angles keep LDS at 38,880 B so 4 blocks/CU is preserved
// (R9's 2-blk/CU latency exposure avoided). Consume: 2 chunks x 256 px,
// 90 angles per chunk per pass. u-arithmetic bit-identical to R7.
__global__ __launch_bounds__(512) void fbp_kernel(
    const float* __restrict__ sino,   // (N,1,A,M)
    const float* __restrict__ theta,  // (A)
    const float* __restrict__ cxs,    // (NP)
    const float* __restrict__ cys,    // (NP)
    float* __restrict__ out)          // (N,NP,PS,PS)
{
    __shared__ float2 win2[PASS_A * W_];           // 34560 B: {g0, g1-g0}
    __shared__ alignas(16) float csA[A_];          // 1440 B: cos*half
    __shared__ alignas(16) float syA[A_];          // 1440 B: sin*half
    __shared__ alignas(16) float ofA[A_];          // 1440 B: half - lo => 38880 B

    const float half = 255.5f;        // (M-1)/2
    const int tid = threadIdx.x;

    const int bid    = blockIdx.x;
    const int region = bid & 15;
    const int p      = (bid >> 4) & (NP_ - 1);
    const int n      = bid >> 9;
    const int ri     = (region >> 2) << 4;
    const int rj     = (region &  3) << 4;

    const float cx = cxs[p];
    const float cy = cys[p];

    // Region corner coords (same op sequence as per-pixel => covering bounds)
    const float gX0 = ((float)(ri      - PS_ / 2) + cx) / half - 1.0f;
    const float gX1 = ((float)(ri + 15 - PS_ / 2) + cx) / half - 1.0f;
    const float gy0 = ((float)(rj      - PS_ / 2) + cy) / half - 1.0f;
    const float gy1 = ((float)(rj + 15 - PS_ / 2) + cy) / half - 1.0f;

    // Phase A: per-angle trig + window origin (offs = half - lo, exact)
    if (tid < A_) {
        const float th  = theta[tid];
        const float csx = cosf(th) * half;
        const float csy = sinf(th) * half;
        const float t0  = fmaf(-gy0, csy, half);
        const float t1  = fmaf(-gy1, csy, half);
        const float u00 = fmaf(gX0, csx, t0);
        const float u10 = fmaf(gX1, csx, t0);
        const float u01 = fmaf(gX0, csx, t1);
        const float u11 = fmaf(gX1, csx, t1);
        const float lof = floorf(fminf(fminf(u00, u10), fminf(u01, u11)));
        csA[tid] = csx;  syA[tid] = csy;  ofA[tid] = half - lof;
    }
    __syncthreads();

    const int chunk = tid >> 8;       // 0 or 1 (angle chunk within pass)
    const int t     = tid & 255;      // pixel slot
    const int i     = ri + (t >> 4);
    const int j     = rj + (t & 15);

    const float gX  = ((float)(i - PS_ / 2) + cx) / half - 1.0f;
    const float gy  = ((float)(j - PS_ / 2) + cy) / half - 1.0f;
    const float ngy = -gy;

    float accG = 0.0f, accW = 0.0f;

    const float* __restrict__ sbase = sino + n * (A_ * M_);

    for (int pass = 0; pass < 2; ++pass) {
        // Phase B: stage this pass's pair-windows {g0, g1-g0}
        const float* __restrict__ srow = sbase + pass * (PASS_A * M_);
        for (int e = tid; e < PASS_A * W_; e += 512) {
            const int al = e / W_;               // staged-local angle 0..179
            const int k  = e - al * W_;
            const int a  = pass * PASS_A + al;   // global angle
            const int lo = (int)(half - ofA[a]); // exact recovery
            const int i0 = min(max(lo + k,     0), M_ - 1);
            const int i1 = min(max(lo + k + 1, 0), M_ - 1);
            const float g0 = srow[al * M_ + i0];
            const float g1 = srow[al * M_ + i1];
            win2[e] = make_float2(g0, g1 - g0);
        }
        __syncthreads();

        // Phase C: this chunk's 90 angles, ONE ds_read_b64 per pixel-angle
        const int abase = pass * PASS_A + chunk * 90;   // global angle base
        const int lbase = chunk * 90;                   // staged-local base
        #pragma unroll 3
        for (int g = 0; g < 45; ++g) {
            const float2 c2 = *(const float2*)&csA[abase + 2 * g];
            const float2 s2 = *(const float2*)&syA[abase + 2 * g];
            const float2 o2 = *(const float2*)&ofA[abase + 2 * g];
            const float2* wr = win2 + (lbase + 2 * g) * W_;
            {
                float u = fmaf(gX, c2.x, fmaf(ngy, s2.x, o2.x));
                u = fminf(fmaxf(u, 0.0f), 22.999f);
                const float2 gg = wr[(int)u];
                accG += gg.x;
                accW  = fmaf(__builtin_amdgcn_fractf(u), gg.y, accW);
            }
            {
                float u = fmaf(gX, c2.y, fmaf(ngy, s2.y, o2.y));
                u = fminf(fmaxf(u, 0.0f), 22.999f);
                const float2 gg = wr[W_ + (int)u];
                accG += gg.x;
                accW  = fmaf(__builtin_amdgcn_fractf(u), gg.y, accW);
            }
        }
        __syncthreads();
    }

    // Cross-chunk reduction (reuse win2 space; synced above)
    float part = accG + accW;
    float* red = (float*)win2;
    if (chunk == 1) red[t] = part;
    __syncthreads();
    if (chunk == 0) {
        part += red[t];
        const float inside = (fmaf(gX, gX, gy * gy) <= 1.0f) ? 1.0f : 0.0f;
        const float scale  = (float)(M_PI / (2.0 * (double)A_));
        out[(((n * NP_) + p) * PS_ + i) * PS_ + j] = part * inside * scale;
    }
}

extern "C" void kernel_launch(void* const* d_in, const int* in_sizes, int n_in,
                              void* d_out, int out_size, void* d_ws, size_t ws_size,
                              hipStream_t stream) {
    const float* sino  = (const float*)d_in[0];
    const float* theta = (const float*)d_in[1];
    const float* cxs   = (const float*)d_in[2];
    const float* cys   = (const float*)d_in[3];
    float* out = (float*)d_out;

    const int blocks = N_ * NP_ * (PS_ * PS_ / 256);  // 1024
    fbp_kernel<<<dim3(blocks), dim3(512), 0, stream>>>(sino, theta, cxs, cys, out);
}

// Round 14
// 31.273 us; speedup vs baseline: 1.0634x; 1.0634x over previous
//
#include <hip/hip_runtime.h>
#include <hip/hip_fp16.h>
#include <math.h>

#define N_  2
#define A_  360
#define M_  512
#define NP_ 32
#define PS_ 64
#define HALF_A 180
#define W_  24            // half2 pairs per window (16x16 span <= 21.3 + interp + slack)

// R7 structure (single stage, 16x16 region, two 256-thread angle-teams), but
// windows packed as half2{g0, g1-g0}: the divergent gather is ONE ds_read_b32
// (4 B/lane) -- HALF the LDS bandwidth of R7's 8 B/lane. fp16 error (~2^-11
// rel, |g|<~6) adds ~3e-5 to the output -- far under the 3.09e-3 threshold.
// LDS = 39,904 B -> 4 blocks/CU.
__global__ __launch_bounds__(512) void fbp_kernel(
    const float* __restrict__ sino,   // (N,1,A,M)
    const float* __restrict__ theta,  // (A)
    const float* __restrict__ cxs,    // (NP)
    const float* __restrict__ cys,    // (NP)
    float* __restrict__ out)          // (N,NP,PS,PS)
{
    __shared__ __half2 win[A_ * W_];               // 34560 B: {g0, g1-g0} fp16
    __shared__ alignas(16) float csA[A_];          // 1440 B: cos*half
    __shared__ alignas(16) float syA[A_];          // 1440 B: sin*half
    __shared__ alignas(16) float ofA[A_];          // 1440 B: half - lo
    __shared__ float red[256];                     // 1024 B  => 39904 B total

    const float half = 255.5f;        // (M-1)/2
    const int tid = threadIdx.x;

    const int bid    = blockIdx.x;
    const int region = bid & 15;            // 4x4 regions per 64x64 patch
    const int p      = (bid >> 4) & (NP_ - 1);
    const int n      = bid >> 9;
    const int ri     = (region >> 2) << 4;
    const int rj     = (region &  3) << 4;

    const float cx = cxs[p];
    const float cy = cys[p];

    // Region corner coords (same op sequence as per-pixel => covering bounds)
    const float gX0 = ((float)(ri      - PS_ / 2) + cx) / half - 1.0f;
    const float gX1 = ((float)(ri + 15 - PS_ / 2) + cx) / half - 1.0f;
    const float gy0 = ((float)(rj      - PS_ / 2) + cy) / half - 1.0f;
    const float gy1 = ((float)(rj + 15 - PS_ / 2) + cy) / half - 1.0f;

    // Phase A: per-angle trig + window origin (fused as offs = half - lo)
    if (tid < A_) {
        const float th  = theta[tid];
        const float csx = cosf(th) * half;
        const float csy = sinf(th) * half;
        const float t0  = fmaf(-gy0, csy, half);
        const float t1  = fmaf(-gy1, csy, half);
        const float u00 = fmaf(gX0, csx, t0);
        const float u10 = fmaf(gX1, csx, t0);
        const float u01 = fmaf(gX0, csx, t1);
        const float u11 = fmaf(gX1, csx, t1);
        const float lof = floorf(fminf(fminf(u00, u10), fminf(u01, u11)));
        csA[tid] = csx;
        syA[tid] = csy;
        ofA[tid] = half - lof;        // exact: lof integer, half = 255.5
    }
    __syncthreads();

    // Phase B: stage packed windows {g0, g1-g0} as half2 (coalesced reads)
    const float* __restrict__ srow = sino + n * (A_ * M_);
    for (int e = tid; e < A_ * W_; e += 512) {
        const int a  = e / W_;
        const int k  = e - a * W_;
        const int lo = (int)(half - ofA[a]);       // exact recovery
        const int i0 = min(max(lo + k,     0), M_ - 1);
        const int i1 = min(max(lo + k + 1, 0), M_ - 1);
        const float g0 = srow[a * M_ + i0];
        const float g1 = srow[a * M_ + i1];
        win[e] = __floats2half2_rn(g0, g1 - g0);
    }
    __syncthreads();

    // Phase C: 180 angles per team, ONE ds_read_b32 gather per pixel-angle
    const int team = tid >> 8;
    const int t    = tid & 255;
    const int i    = ri + (t >> 4);
    const int j    = rj + (t & 15);

    const float gX  = ((float)(i - PS_ / 2) + cx) / half - 1.0f;
    const float gy  = ((float)(j - PS_ / 2) + cy) / half - 1.0f;
    const float ngy = -gy;

    const int gbase = team * (HALF_A / 4);         // float4 group index
    const float4* __restrict__ cs4 = (const float4*)csA;
    const float4* __restrict__ sy4 = (const float4*)syA;
    const float4* __restrict__ of4 = (const float4*)ofA;

    float accG = 0.0f;
    float accW = 0.0f;
    const __half2* wp0 = win + team * (HALF_A * W_);

    #pragma unroll 3
    for (int g = 0; g < HALF_A / 4; ++g) {
        const float4 c4 = cs4[gbase + g];
        const float4 s4 = sy4[gbase + g];
        const float4 o4 = of4[gbase + g];
        const __half2* wp = wp0 + g * (4 * W_);

        {   // sub-iter 0
            float u = fmaf(gX, c4.x, fmaf(ngy, s4.x, o4.x));
            u = fminf(fmaxf(u, 0.0f), 22.999f);
            const float2 gg = __half22float2(wp[(int)u]);
            accG += gg.x;  accW = fmaf(__builtin_amdgcn_fractf(u), gg.y, accW);
        }
        {   // sub-iter 1
            float u = fmaf(gX, c4.y, fmaf(ngy, s4.y, o4.y));
            u = fminf(fmaxf(u, 0.0f), 22.999f);
            const float2 gg = __half22float2(wp[W_ + (int)u]);
            accG += gg.x;  accW = fmaf(__builtin_amdgcn_fractf(u), gg.y, accW);
        }
        {   // sub-iter 2
            float u = fmaf(gX, c4.z, fmaf(ngy, s4.z, o4.z));
            u = fminf(fmaxf(u, 0.0f), 22.999f);
            const float2 gg = __half22float2(wp[2 * W_ + (int)u]);
            accG += gg.x;  accW = fmaf(__builtin_amdgcn_fractf(u), gg.y, accW);
        }
        {   // sub-iter 3
            float u = fmaf(gX, c4.w, fmaf(ngy, s4.w, o4.w));
            u = fminf(fmaxf(u, 0.0f), 22.999f);
            const float2 gg = __half22float2(wp[3 * W_ + (int)u]);
            accG += gg.x;  accW = fmaf(__builtin_amdgcn_fractf(u), gg.y, accW);
        }
    }

    const float part = accG + accW;
    if (team == 1) red[t] = part;
    __syncthreads();
    if (team == 0) {
        const float inside = (fmaf(gX, gX, gy * gy) <= 1.0f) ? 1.0f : 0.0f;
        const float scale  = (float)(M_PI / (2.0 * (double)A_));
        out[(((n * NP_) + p) * PS_ + i) * PS_ + j] =
            (part + red[t]) * inside * scale;
    }
}

extern "C" void kernel_launch(void* const* d_in, const int* in_sizes, int n_in,
                              void* d_out, int out_size, void* d_ws, size_t ws_size,
                              hipStream_t stream) {
    const float* sino  = (const float*)d_in[0];
    const float* theta = (const float*)d_in[1];
    const float* cxs   = (const float*)d_in[2];
    const float* cys   = (const float*)d_in[3];
    float* out = (float*)d_out;

    const int blocks = N_ * NP_ * (PS_ * PS_ / 256);  // 1024
    fbp_kernel<<<dim3(blocks), dim3(512), 0, stream>>>(sino, theta, cxs, cys, out);
}